// Round 1
// baseline (7007.849 us; speedup 1.0000x reference)
//
#include <hip/hip_runtime.h>

#define N_NODES 50000
#define N_EDGES 1600000
#define NHEAD 8
#define DH 16
#define D_IN 8
#define E_IN_DIM 12
#define HID 128
#define GRAPHS 64

// ---------------- node pass 1: x = concat(pos, emb[z]);  qk[n,h,j] = scale * sum_d q[n,h,d]*Wk[j,16h+d]
__global__ __launch_bounds__(256) void k_node1(
    const float* __restrict__ pos, const int* __restrict__ z,
    const float* __restrict__ emb,
    const float* __restrict__ Wq, const float* __restrict__ Wk,
    float* __restrict__ x, float* __restrict__ qk)
{
    __shared__ float sWq[D_IN * HID];     // 1024 floats
    __shared__ float sWk[E_IN_DIM * HID]; // 1536 floats
    __shared__ float sx[32][D_IN];

    int tid = threadIdx.x;
    for (int i = tid; i < D_IN * HID; i += 256) sWq[i] = Wq[i];
    for (int i = tid; i < E_IN_DIM * HID; i += 256) sWk[i] = Wk[i];

    int nl = tid >> 3;      // 0..31 local node
    int h  = tid & 7;       // head (also reused as feature index j in phase A)
    int n  = blockIdx.x * 32 + nl;

    if (n < N_NODES) {
        int j = h;  // 8 features, 8 threads per node
        float v;
        if (j < 3) v = pos[n * 3 + j];
        else       v = emb[z[n] * 5 + (j - 3)];
        sx[nl][j] = v;
        x[n * D_IN + j] = v;
    }
    __syncthreads();
    if (n >= N_NODES) return;

    float q[DH];
    #pragma unroll
    for (int d = 0; d < DH; ++d) {
        float acc = 0.f;
        #pragma unroll
        for (int j = 0; j < D_IN; ++j)
            acc += sx[nl][j] * sWq[j * HID + h * DH + d];
        q[d] = acc;
    }
    const float scale = 0.25f;  // 1/sqrt(DH)
    #pragma unroll
    for (int j = 0; j < E_IN_DIM; ++j) {
        float acc = 0.f;
        #pragma unroll
        for (int d = 0; d < DH; ++d)
            acc += q[d] * sWk[j * HID + h * DH + d];
        qk[n * 96 + h * 12 + j] = acc * scale;
    }
}

// ---------------- edge pass: one thread per (edge, head)
__global__ __launch_bounds__(256) void k_edge(
    const int* __restrict__ edge_index, const float* __restrict__ edge_attr,
    const float* __restrict__ x, const float* __restrict__ qk,
    float* __restrict__ denom, float* __restrict__ s)
{
    int gid = blockIdx.x * 256 + threadIdx.x;
    int e = gid >> 3;
    int h = gid & 7;
    if (e >= N_EDGES) return;

    int src = edge_index[e];
    int dst = edge_index[N_EDGES + e];

    float ein[12];
    const float4* xp = (const float4*)(x + src * 8);
    float4 x0 = xp[0], x1 = xp[1];
    ein[0] = x0.x; ein[1] = x0.y; ein[2] = x0.z; ein[3] = x0.w;
    ein[4] = x1.x; ein[5] = x1.y; ein[6] = x1.z; ein[7] = x1.w;
    float4 ea = ((const float4*)edge_attr)[e];
    ein[8] = ea.x; ein[9] = ea.y; ein[10] = ea.z; ein[11] = ea.w;

    const float4* qr = (const float4*)(qk + dst * 96 + h * 12);
    float4 q0 = qr[0], q1 = qr[1], q2 = qr[2];

    float sc = ein[0]*q0.x + ein[1]*q0.y + ein[2]*q0.z + ein[3]*q0.w
             + ein[4]*q1.x + ein[5]*q1.y + ein[6]*q1.z + ein[7]*q1.w
             + ein[8]*q2.x + ein[9]*q2.y + ein[10]*q2.z + ein[11]*q2.w;

    float ex = __expf(sc);

    atomicAdd(&denom[dst * 8 + h], ex);
    float* srow = s + dst * 96 + h * 12;
    #pragma unroll
    for (int j = 0; j < 12; ++j)
        atomicAdd(&srow[j], ex * ein[j]);
}

// ---------------- node pass 2: agg = (s@Wv)/denom; feats = agg@Wo; relu; y = feats@lin_W + b; pool
__global__ __launch_bounds__(256) void k_node2(
    const float* __restrict__ denom, const float* __restrict__ s,
    const float* __restrict__ Wv, const float* __restrict__ Wo,
    const float* __restrict__ lin_W, const float* __restrict__ lin_b,
    const int* __restrict__ batch,
    float* __restrict__ gsum, float* __restrict__ gcnt)
{
    __shared__ float sWv[E_IN_DIM * HID];  // 1536 floats
    __shared__ float aggl[32][HID + 1];    // +1 pad: avoid 8-way LDS bank conflict

    int tid = threadIdx.x;
    for (int i = tid; i < E_IN_DIM * HID; i += 256) sWv[i] = Wv[i];

    int nl = tid >> 3, h = tid & 7;
    int n = blockIdx.x * 32 + nl;
    __syncthreads();

    if (n < N_NODES) {
        float dn  = denom[n * 8 + h];
        float inv = 1.0f / fmaxf(dn, 1e-9f);
        float sr[12];
        const float4* sp = (const float4*)(s + n * 96 + h * 12);
        float4 a = sp[0], b = sp[1], c = sp[2];
        sr[0]=a.x; sr[1]=a.y; sr[2]=a.z; sr[3]=a.w;
        sr[4]=b.x; sr[5]=b.y; sr[6]=b.z; sr[7]=b.w;
        sr[8]=c.x; sr[9]=c.y; sr[10]=c.z; sr[11]=c.w;
        #pragma unroll
        for (int d = 0; d < DH; ++d) {
            float acc = 0.f;
            #pragma unroll
            for (int j = 0; j < E_IN_DIM; ++j)
                acc += sr[j] * sWv[j * HID + h * DH + d];
            aggl[nl][h * DH + d] = acc * inv;
        }
    }
    __syncthreads();

    float partial = 0.f;
    if (n < N_NODES) {
        float f[16];
        #pragma unroll
        for (int d = 0; d < 16; ++d) f[d] = 0.f;
        const float* wbase = Wo + h * DH;
        for (int i = 0; i < HID; ++i) {
            float av = aggl[nl][i];
            const float4* wr = (const float4*)(wbase + i * HID);
            float4 w0 = wr[0], w1 = wr[1], w2 = wr[2], w3 = wr[3];
            f[0]  += av * w0.x; f[1]  += av * w0.y; f[2]  += av * w0.z; f[3]  += av * w0.w;
            f[4]  += av * w1.x; f[5]  += av * w1.y; f[6]  += av * w1.z; f[7]  += av * w1.w;
            f[8]  += av * w2.x; f[9]  += av * w2.y; f[10] += av * w2.z; f[11] += av * w2.w;
            f[12] += av * w3.x; f[13] += av * w3.y; f[14] += av * w3.z; f[15] += av * w3.w;
        }
        #pragma unroll
        for (int d = 0; d < 16; ++d) {
            float r = fmaxf(f[d], 0.f);
            partial += r * lin_W[h * DH + d];
        }
    }
    // reduce over the 8 head-lanes (consecutive lanes in wave)
    partial += __shfl_xor(partial, 1);
    partial += __shfl_xor(partial, 2);
    partial += __shfl_xor(partial, 4);

    if (n < N_NODES && h == 0) {
        float y = partial + lin_b[0];
        int g = batch[n];
        atomicAdd(&gsum[g], y);
        atomicAdd(&gcnt[g], 1.0f);
    }
}

__global__ void k_final(const float* __restrict__ gsum, const float* __restrict__ gcnt,
                        float* __restrict__ out)
{
    int g = threadIdx.x;
    if (g < GRAPHS) out[g] = gsum[g] / fmaxf(gcnt[g], 1.0f);
}

extern "C" void kernel_launch(void* const* d_in, const int* in_sizes, int n_in,
                              void* d_out, int out_size, void* d_ws, size_t ws_size,
                              hipStream_t stream)
{
    const float* pos       = (const float*)d_in[0];
    const int*   z         = (const int*)  d_in[1];
    const int*   edge_index= (const int*)  d_in[2];
    const float* edge_attr = (const float*)d_in[3];
    const int*   batch     = (const int*)  d_in[4];
    const float* emb       = (const float*)d_in[5];
    const float* Wq        = (const float*)d_in[6];
    const float* Wk        = (const float*)d_in[7];
    const float* Wv        = (const float*)d_in[8];
    const float* Wo        = (const float*)d_in[9];
    const float* lin_W     = (const float*)d_in[10];
    const float* lin_b     = (const float*)d_in[11];
    float* out = (float*)d_out;

    float* ws    = (float*)d_ws;
    float* denom = ws;                          // N*8
    float* s     = denom + N_NODES * 8;         // N*96
    float* gsum  = s + N_NODES * 96;            // GRAPHS
    float* gcnt  = gsum + GRAPHS;               // GRAPHS
    float* x     = gcnt + GRAPHS;               // N*8
    float* qk    = x + N_NODES * 8;             // N*96

    size_t zero_bytes = (size_t)(N_NODES * 8 + N_NODES * 96 + 2 * GRAPHS) * sizeof(float);
    hipMemsetAsync(denom, 0, zero_bytes, stream);

    k_node1<<<(N_NODES + 31) / 32, 256, 0, stream>>>(pos, z, emb, Wq, Wk, x, qk);
    k_edge<<<(N_EDGES * 8) / 256, 256, 0, stream>>>(edge_index, edge_attr, x, qk, denom, s);
    k_node2<<<(N_NODES + 31) / 32, 256, 0, stream>>>(denom, s, Wv, Wo, lin_W, lin_b, batch, gsum, gcnt);
    k_final<<<1, 64, 0, stream>>>(gsum, gcnt, out);
}

// Round 2
// 851.336 us; speedup vs baseline: 8.2316x; 8.2316x over previous
//
#include <hip/hip_runtime.h>

#define N_NODES 50000
#define N_EDGES 1600000
#define NHEAD 8
#define DH 16
#define D_IN 8
#define E_IN_DIM 12
#define HID 128
#define GRAPHS 64

// ---------------- node pass 1: x = concat(pos, emb[z]);  qk[n,h,j] = scale * sum_d q[n,h,d]*Wk[j,16h+d]
__global__ __launch_bounds__(256) void k_node1(
    const float* __restrict__ pos, const int* __restrict__ z,
    const float* __restrict__ emb,
    const float* __restrict__ Wq, const float* __restrict__ Wk,
    float* __restrict__ x, float* __restrict__ qk)
{
    __shared__ float sWq[D_IN * HID];     // 1024 floats
    __shared__ float sWk[E_IN_DIM * HID]; // 1536 floats
    __shared__ float sx[32][D_IN];

    int tid = threadIdx.x;
    for (int i = tid; i < D_IN * HID; i += 256) sWq[i] = Wq[i];
    for (int i = tid; i < E_IN_DIM * HID; i += 256) sWk[i] = Wk[i];

    int nl = tid >> 3;      // 0..31 local node
    int h  = tid & 7;       // head
    int n  = blockIdx.x * 32 + nl;

    if (n < N_NODES) {
        int j = h;  // 8 features, 8 threads per node
        float v;
        if (j < 3) v = pos[n * 3 + j];
        else       v = emb[z[n] * 5 + (j - 3)];
        sx[nl][j] = v;
        x[n * D_IN + j] = v;
    }
    __syncthreads();
    if (n >= N_NODES) return;

    float q[DH];
    #pragma unroll
    for (int d = 0; d < DH; ++d) {
        float acc = 0.f;
        #pragma unroll
        for (int j = 0; j < D_IN; ++j)
            acc += sx[nl][j] * sWq[j * HID + h * DH + d];
        q[d] = acc;
    }
    const float scale = 0.25f;  // 1/sqrt(DH)
    #pragma unroll
    for (int j = 0; j < E_IN_DIM; ++j) {
        float acc = 0.f;
        #pragma unroll
        for (int d = 0; d < DH; ++d)
            acc += q[d] * sWk[j * HID + h * DH + d];
        qk[n * 96 + h * 12 + j] = acc * scale;
    }
}

// ---------------- histogram of dst
__global__ __launch_bounds__(256) void k_hist(
    const int* __restrict__ edge_index, int* __restrict__ counts)
{
    int e = blockIdx.x * 256 + threadIdx.x;
    if (e < N_EDGES) atomicAdd(&counts[edge_index[N_EDGES + e]], 1);
}

// ---------------- exclusive scan over 50K counts (single block)
#define SCAN_T 1024
__global__ __launch_bounds__(1024) void k_scan(
    const int* __restrict__ counts, int* __restrict__ offsets, int* __restrict__ woff)
{
    __shared__ int lsum[SCAN_T];
    int t = threadIdx.x;
    const int CH = (N_NODES + SCAN_T - 1) / SCAN_T;  // 49
    int beg = t * CH, end = min(beg + CH, N_NODES);
    int s = 0;
    for (int i = beg; i < end; ++i) s += counts[i];
    lsum[t] = s;
    __syncthreads();
    for (int off = 1; off < SCAN_T; off <<= 1) {
        int v = 0;
        if (t >= off) v = lsum[t - off];
        __syncthreads();
        if (t >= off) lsum[t] += v;
        __syncthreads();
    }
    int pre = (t == 0) ? 0 : lsum[t - 1];
    for (int i = beg; i < end; ++i) {
        offsets[i] = pre; woff[i] = pre;
        pre += counts[i];
    }
    if (t == SCAN_T - 1) offsets[N_NODES] = pre;  // == N_EDGES
}

// ---------------- scatter edges into dst-sorted order
__global__ __launch_bounds__(256) void k_scatter(
    const int* __restrict__ edge_index, int* __restrict__ woff,
    int2* __restrict__ sorted)
{
    int e = blockIdx.x * 256 + threadIdx.x;
    if (e >= N_EDGES) return;
    int src = edge_index[e];
    int dst = edge_index[N_EDGES + e];
    int pos = atomicAdd(&woff[dst], 1);
    sorted[pos] = make_int2(src, e);
}

// ---------------- fused per-node pass: softmax-agg over own edges (registers), @Wv, @Wo, relu, @lin_W, pool
__global__ __launch_bounds__(256) void k_nodeD(
    const int* __restrict__ offsets, const int2* __restrict__ sorted,
    const float* __restrict__ x, const float* __restrict__ qk,
    const float* __restrict__ edge_attr,
    const float* __restrict__ Wv, const float* __restrict__ Wo,
    const float* __restrict__ lin_W, const float* __restrict__ lin_b,
    const int* __restrict__ batch,
    float* __restrict__ gsum, float* __restrict__ gcnt)
{
    __shared__ float sWv[E_IN_DIM * HID];  // 1536 floats
    __shared__ float aggl[32][HID + 1];    // +1 pad

    int tid = threadIdx.x;
    for (int i = tid; i < E_IN_DIM * HID; i += 256) sWv[i] = Wv[i];

    int nl = tid >> 3, h = tid & 7;
    int n = blockIdx.x * 32 + nl;
    __syncthreads();

    if (n < N_NODES) {
        const float4* qr = (const float4*)(qk + n * 96 + h * 12);
        float4 q0 = qr[0], q1 = qr[1], q2 = qr[2];

        float sr[12];
        #pragma unroll
        for (int j = 0; j < 12; ++j) sr[j] = 0.f;
        float denom = 0.f;

        int beg = offsets[n], end = offsets[n + 1];
        for (int i = beg; i < end; ++i) {
            int2 p = sorted[i];
            const float4* xp = (const float4*)(x + p.x * 8);
            float4 x0 = xp[0], x1 = xp[1];
            float4 ea = ((const float4*)edge_attr)[p.y];
            float sc = x0.x*q0.x + x0.y*q0.y + x0.z*q0.z + x0.w*q0.w
                     + x1.x*q1.x + x1.y*q1.y + x1.z*q1.z + x1.w*q1.w
                     + ea.x*q2.x + ea.y*q2.y + ea.z*q2.z + ea.w*q2.w;
            float ex = __expf(sc);
            denom += ex;
            sr[0] += ex * x0.x; sr[1]  += ex * x0.y; sr[2]  += ex * x0.z; sr[3]  += ex * x0.w;
            sr[4] += ex * x1.x; sr[5]  += ex * x1.y; sr[6]  += ex * x1.z; sr[7]  += ex * x1.w;
            sr[8] += ex * ea.x; sr[9]  += ex * ea.y; sr[10] += ex * ea.z; sr[11] += ex * ea.w;
        }
        float inv = 1.0f / fmaxf(denom, 1e-9f);
        #pragma unroll
        for (int d = 0; d < DH; ++d) {
            float acc = 0.f;
            #pragma unroll
            for (int j = 0; j < E_IN_DIM; ++j)
                acc += sr[j] * sWv[j * HID + h * DH + d];
            aggl[nl][h * DH + d] = acc * inv;
        }
    }
    __syncthreads();

    float partial = 0.f;
    if (n < N_NODES) {
        float f[16];
        #pragma unroll
        for (int d = 0; d < 16; ++d) f[d] = 0.f;
        const float* wbase = Wo + h * DH;
        for (int i = 0; i < HID; ++i) {
            float av = aggl[nl][i];
            const float4* wr = (const float4*)(wbase + i * HID);
            float4 w0 = wr[0], w1 = wr[1], w2 = wr[2], w3 = wr[3];
            f[0]  += av * w0.x; f[1]  += av * w0.y; f[2]  += av * w0.z; f[3]  += av * w0.w;
            f[4]  += av * w1.x; f[5]  += av * w1.y; f[6]  += av * w1.z; f[7]  += av * w1.w;
            f[8]  += av * w2.x; f[9]  += av * w2.y; f[10] += av * w2.z; f[11] += av * w2.w;
            f[12] += av * w3.x; f[13] += av * w3.y; f[14] += av * w3.z; f[15] += av * w3.w;
        }
        #pragma unroll
        for (int d = 0; d < 16; ++d) {
            float r = fmaxf(f[d], 0.f);
            partial += r * lin_W[h * DH + d];
        }
    }
    partial += __shfl_xor(partial, 1);
    partial += __shfl_xor(partial, 2);
    partial += __shfl_xor(partial, 4);

    if (n < N_NODES && h == 0) {
        float y = partial + lin_b[0];
        int g = batch[n];
        atomicAdd(&gsum[g], y);
        atomicAdd(&gcnt[g], 1.0f);
    }
}

__global__ void k_final(const float* __restrict__ gsum, const float* __restrict__ gcnt,
                        float* __restrict__ out)
{
    int g = threadIdx.x;
    if (g < GRAPHS) out[g] = gsum[g] / fmaxf(gcnt[g], 1.0f);
}

extern "C" void kernel_launch(void* const* d_in, const int* in_sizes, int n_in,
                              void* d_out, int out_size, void* d_ws, size_t ws_size,
                              hipStream_t stream)
{
    const float* pos       = (const float*)d_in[0];
    const int*   z         = (const int*)  d_in[1];
    const int*   edge_index= (const int*)  d_in[2];
    const float* edge_attr = (const float*)d_in[3];
    const int*   batch     = (const int*)  d_in[4];
    const float* emb       = (const float*)d_in[5];
    const float* Wq        = (const float*)d_in[6];
    const float* Wk        = (const float*)d_in[7];
    const float* Wv        = (const float*)d_in[8];
    const float* Wo        = (const float*)d_in[9];
    const float* lin_W     = (const float*)d_in[10];
    const float* lin_b     = (const float*)d_in[11];
    float* out = (float*)d_out;

    // workspace layout (all 16B-aligned)
    char* ws = (char*)d_ws;
    int*   counts  = (int*)ws;                         // 50000 ints
    float* gsum    = (float*)(counts + N_NODES);       // 64
    float* gcnt    = gsum + GRAPHS;                    // 64   -> counts..gcnt = 50128 elems (200512 B, %16==0)
    int*   offsets = (int*)(gcnt + GRAPHS);            // 50004 ints (padded, %16 B aligned after)
    int*   woff    = offsets + 50004;                  // 50000 ints
    int2*  sorted  = (int2*)(woff + N_NODES);          // 1.6M int2 (12.8 MB)
    float* x       = (float*)(sorted + N_EDGES);       // N*8 floats (1.6 MB)
    float* qk      = x + N_NODES * 8;                  // N*96 floats (19.2 MB)

    // zero counts + gsum + gcnt in one shot (they are contiguous)
    hipMemsetAsync(counts, 0, (size_t)(N_NODES + 2 * GRAPHS) * sizeof(int), stream);

    k_node1  <<<(N_NODES + 31) / 32, 256, 0, stream>>>(pos, z, emb, Wq, Wk, x, qk);
    k_hist   <<<(N_EDGES + 255) / 256, 256, 0, stream>>>(edge_index, counts);
    k_scan   <<<1, SCAN_T, 0, stream>>>(counts, offsets, woff);
    k_scatter<<<(N_EDGES + 255) / 256, 256, 0, stream>>>(edge_index, woff, sorted);
    k_nodeD  <<<(N_NODES + 31) / 32, 256, 0, stream>>>(offsets, sorted, x, qk, edge_attr,
                                                       Wv, Wo, lin_W, lin_b, batch, gsum, gcnt);
    k_final  <<<1, 64, 0, stream>>>(gsum, gcnt, out);
}

// Round 3
// 796.810 us; speedup vs baseline: 8.7949x; 1.0684x over previous
//
#include <hip/hip_runtime.h>

#define N_NODES 50000
#define N_EDGES 1600000
#define NHEAD 8
#define DH 16
#define D_IN 8
#define E_IN_DIM 12
#define HID 128
#define GRAPHS 64

// ---------------- node pass 1: x = concat(pos, emb[z]);  qk[n,h,j] = scale * sum_d q[n,h,d]*Wk[j,16h+d]
__global__ __launch_bounds__(256) void k_node1(
    const float* __restrict__ pos, const int* __restrict__ z,
    const float* __restrict__ emb,
    const float* __restrict__ Wq, const float* __restrict__ Wk,
    float* __restrict__ x, float* __restrict__ qk)
{
    __shared__ float sWq[D_IN * HID];
    __shared__ float sWk[E_IN_DIM * HID];
    __shared__ float sx[32][D_IN];

    int tid = threadIdx.x;
    for (int i = tid; i < D_IN * HID; i += 256) sWq[i] = Wq[i];
    for (int i = tid; i < E_IN_DIM * HID; i += 256) sWk[i] = Wk[i];

    int nl = tid >> 3;
    int h  = tid & 7;
    int n  = blockIdx.x * 32 + nl;

    if (n < N_NODES) {
        int j = h;
        float v;
        if (j < 3) v = pos[n * 3 + j];
        else       v = emb[z[n] * 5 + (j - 3)];
        sx[nl][j] = v;
        x[n * D_IN + j] = v;
    }
    __syncthreads();
    if (n >= N_NODES) return;

    float q[DH];
    #pragma unroll
    for (int d = 0; d < DH; ++d) {
        float acc = 0.f;
        #pragma unroll
        for (int j = 0; j < D_IN; ++j)
            acc += sx[nl][j] * sWq[j * HID + h * DH + d];
        q[d] = acc;
    }
    const float scale = 0.25f;
    #pragma unroll
    for (int j = 0; j < E_IN_DIM; ++j) {
        float acc = 0.f;
        #pragma unroll
        for (int d = 0; d < DH; ++d)
            acc += q[d] * sWk[j * HID + h * DH + d];
        qk[n * 96 + h * 12 + j] = acc * scale;
    }
}

// ---------------- histogram of dst
__global__ __launch_bounds__(256) void k_hist(
    const int* __restrict__ edge_index, int* __restrict__ counts)
{
    int e = blockIdx.x * 256 + threadIdx.x;
    if (e < N_EDGES) atomicAdd(&counts[edge_index[N_EDGES + e]], 1);
}

// ---------------- exclusive scan over 50K counts (single block)
#define SCAN_T 1024
__global__ __launch_bounds__(1024) void k_scan(
    const int* __restrict__ counts, int* __restrict__ offsets, int* __restrict__ woff)
{
    __shared__ int lsum[SCAN_T];
    int t = threadIdx.x;
    const int CH = (N_NODES + SCAN_T - 1) / SCAN_T;
    int beg = t * CH, end = min(beg + CH, N_NODES);
    int s = 0;
    for (int i = beg; i < end; ++i) s += counts[i];
    lsum[t] = s;
    __syncthreads();
    for (int off = 1; off < SCAN_T; off <<= 1) {
        int v = 0;
        if (t >= off) v = lsum[t - off];
        __syncthreads();
        if (t >= off) lsum[t] += v;
        __syncthreads();
    }
    int pre = (t == 0) ? 0 : lsum[t - 1];
    for (int i = beg; i < end; ++i) {
        offsets[i] = pre; woff[i] = pre;
        pre += counts[i];
    }
    if (t == SCAN_T - 1) offsets[N_NODES] = pre;
}

// ---------------- scatter: materialize ein = concat(x[src], edge_attr) into dst-sorted order
__global__ __launch_bounds__(256) void k_scatter_ein(
    const int* __restrict__ edge_index, const float* __restrict__ edge_attr,
    const float* __restrict__ x, int* __restrict__ woff,
    float* __restrict__ sein)
{
    int e = blockIdx.x * 256 + threadIdx.x;
    if (e >= N_EDGES) return;
    int src = edge_index[e];
    int dst = edge_index[N_EDGES + e];
    const float4* xp = (const float4*)(x + src * 8);
    float4 x0 = xp[0], x1 = xp[1];
    float4 ea = ((const float4*)edge_attr)[e];
    int pos = atomicAdd(&woff[dst], 1);
    float4* op = (float4*)(sein + (size_t)pos * 12);
    op[0] = x0; op[1] = x1; op[2] = ea;
}

// ---------------- fallback scatter (round-2 path): (src, e) pairs
__global__ __launch_bounds__(256) void k_scatter(
    const int* __restrict__ edge_index, int* __restrict__ woff,
    int2* __restrict__ sorted)
{
    int e = blockIdx.x * 256 + threadIdx.x;
    if (e >= N_EDGES) return;
    int src = edge_index[e];
    int dst = edge_index[N_EDGES + e];
    int pos = atomicAdd(&woff[dst], 1);
    sorted[pos] = make_int2(src, e);
}

// ---------------- fused per-node pass, streaming-ein version
__global__ __launch_bounds__(256) void k_nodeD2(
    const int* __restrict__ offsets, const float* __restrict__ sein,
    const float* __restrict__ qk,
    const float* __restrict__ Wv, const float* __restrict__ Wo,
    const float* __restrict__ lin_W, const float* __restrict__ lin_b,
    const int* __restrict__ batch,
    float* __restrict__ gsum, float* __restrict__ gcnt)
{
    __shared__ float sWv[E_IN_DIM * HID];
    __shared__ float aggl[32][HID + 1];

    int tid = threadIdx.x;
    for (int i = tid; i < E_IN_DIM * HID; i += 256) sWv[i] = Wv[i];

    int nl = tid >> 3, h = tid & 7;
    int n = blockIdx.x * 32 + nl;
    __syncthreads();

    if (n < N_NODES) {
        const float4* qr = (const float4*)(qk + n * 96 + h * 12);
        float4 q0 = qr[0], q1 = qr[1], q2 = qr[2];

        float sr[12];
        #pragma unroll
        for (int j = 0; j < 12; ++j) sr[j] = 0.f;
        float denom = 0.f;

        int beg = offsets[n], end = offsets[n + 1];
        const float4* ep = (const float4*)(sein + (size_t)beg * 12);
        #pragma unroll 4
        for (int i = beg; i < end; ++i, ep += 3) {
            float4 x0 = ep[0], x1 = ep[1], ea = ep[2];
            float sc = x0.x*q0.x + x0.y*q0.y + x0.z*q0.z + x0.w*q0.w
                     + x1.x*q1.x + x1.y*q1.y + x1.z*q1.z + x1.w*q1.w
                     + ea.x*q2.x + ea.y*q2.y + ea.z*q2.z + ea.w*q2.w;
            float ex = __expf(sc);
            denom += ex;
            sr[0] += ex * x0.x; sr[1]  += ex * x0.y; sr[2]  += ex * x0.z; sr[3]  += ex * x0.w;
            sr[4] += ex * x1.x; sr[5]  += ex * x1.y; sr[6]  += ex * x1.z; sr[7]  += ex * x1.w;
            sr[8] += ex * ea.x; sr[9]  += ex * ea.y; sr[10] += ex * ea.z; sr[11] += ex * ea.w;
        }
        float inv = 1.0f / fmaxf(denom, 1e-9f);
        #pragma unroll
        for (int d = 0; d < DH; ++d) {
            float acc = 0.f;
            #pragma unroll
            for (int j = 0; j < E_IN_DIM; ++j)
                acc += sr[j] * sWv[j * HID + h * DH + d];
            aggl[nl][h * DH + d] = acc * inv;
        }
    }
    __syncthreads();

    float partial = 0.f;
    if (n < N_NODES) {
        float f[16];
        #pragma unroll
        for (int d = 0; d < 16; ++d) f[d] = 0.f;
        const float* wbase = Wo + h * DH;
        for (int i = 0; i < HID; ++i) {
            float av = aggl[nl][i];
            const float4* wr = (const float4*)(wbase + i * HID);
            float4 w0 = wr[0], w1 = wr[1], w2 = wr[2], w3 = wr[3];
            f[0]  += av * w0.x; f[1]  += av * w0.y; f[2]  += av * w0.z; f[3]  += av * w0.w;
            f[4]  += av * w1.x; f[5]  += av * w1.y; f[6]  += av * w1.z; f[7]  += av * w1.w;
            f[8]  += av * w2.x; f[9]  += av * w2.y; f[10] += av * w2.z; f[11] += av * w2.w;
            f[12] += av * w3.x; f[13] += av * w3.y; f[14] += av * w3.z; f[15] += av * w3.w;
        }
        #pragma unroll
        for (int d = 0; d < 16; ++d) {
            float r = fmaxf(f[d], 0.f);
            partial += r * lin_W[h * DH + d];
        }
    }
    partial += __shfl_xor(partial, 1);
    partial += __shfl_xor(partial, 2);
    partial += __shfl_xor(partial, 4);

    if (n < N_NODES && h == 0) {
        float y = partial + lin_b[0];
        int g = batch[n];
        atomicAdd(&gsum[g], y);
        atomicAdd(&gcnt[g], 1.0f);
    }
}

// ---------------- fallback fused pass (round-2 path)
__global__ __launch_bounds__(256) void k_nodeD(
    const int* __restrict__ offsets, const int2* __restrict__ sorted,
    const float* __restrict__ x, const float* __restrict__ qk,
    const float* __restrict__ edge_attr,
    const float* __restrict__ Wv, const float* __restrict__ Wo,
    const float* __restrict__ lin_W, const float* __restrict__ lin_b,
    const int* __restrict__ batch,
    float* __restrict__ gsum, float* __restrict__ gcnt)
{
    __shared__ float sWv[E_IN_DIM * HID];
    __shared__ float aggl[32][HID + 1];

    int tid = threadIdx.x;
    for (int i = tid; i < E_IN_DIM * HID; i += 256) sWv[i] = Wv[i];

    int nl = tid >> 3, h = tid & 7;
    int n = blockIdx.x * 32 + nl;
    __syncthreads();

    if (n < N_NODES) {
        const float4* qr = (const float4*)(qk + n * 96 + h * 12);
        float4 q0 = qr[0], q1 = qr[1], q2 = qr[2];
        float sr[12];
        #pragma unroll
        for (int j = 0; j < 12; ++j) sr[j] = 0.f;
        float denom = 0.f;
        int beg = offsets[n], end = offsets[n + 1];
        for (int i = beg; i < end; ++i) {
            int2 p = sorted[i];
            const float4* xp = (const float4*)(x + p.x * 8);
            float4 x0 = xp[0], x1 = xp[1];
            float4 ea = ((const float4*)edge_attr)[p.y];
            float sc = x0.x*q0.x + x0.y*q0.y + x0.z*q0.z + x0.w*q0.w
                     + x1.x*q1.x + x1.y*q1.y + x1.z*q1.z + x1.w*q1.w
                     + ea.x*q2.x + ea.y*q2.y + ea.z*q2.z + ea.w*q2.w;
            float ex = __expf(sc);
            denom += ex;
            sr[0] += ex * x0.x; sr[1]  += ex * x0.y; sr[2]  += ex * x0.z; sr[3]  += ex * x0.w;
            sr[4] += ex * x1.x; sr[5]  += ex * x1.y; sr[6]  += ex * x1.z; sr[7]  += ex * x1.w;
            sr[8] += ex * ea.x; sr[9]  += ex * ea.y; sr[10] += ex * ea.z; sr[11] += ex * ea.w;
        }
        float inv = 1.0f / fmaxf(denom, 1e-9f);
        #pragma unroll
        for (int d = 0; d < DH; ++d) {
            float acc = 0.f;
            #pragma unroll
            for (int j = 0; j < E_IN_DIM; ++j)
                acc += sr[j] * sWv[j * HID + h * DH + d];
            aggl[nl][h * DH + d] = acc * inv;
        }
    }
    __syncthreads();

    float partial = 0.f;
    if (n < N_NODES) {
        float f[16];
        #pragma unroll
        for (int d = 0; d < 16; ++d) f[d] = 0.f;
        const float* wbase = Wo + h * DH;
        for (int i = 0; i < HID; ++i) {
            float av = aggl[nl][i];
            const float4* wr = (const float4*)(wbase + i * HID);
            float4 w0 = wr[0], w1 = wr[1], w2 = wr[2], w3 = wr[3];
            f[0]  += av * w0.x; f[1]  += av * w0.y; f[2]  += av * w0.z; f[3]  += av * w0.w;
            f[4]  += av * w1.x; f[5]  += av * w1.y; f[6]  += av * w1.z; f[7]  += av * w1.w;
            f[8]  += av * w2.x; f[9]  += av * w2.y; f[10] += av * w2.z; f[11] += av * w2.w;
            f[12] += av * w3.x; f[13] += av * w3.y; f[14] += av * w3.z; f[15] += av * w3.w;
        }
        #pragma unroll
        for (int d = 0; d < 16; ++d) {
            float r = fmaxf(f[d], 0.f);
            partial += r * lin_W[h * DH + d];
        }
    }
    partial += __shfl_xor(partial, 1);
    partial += __shfl_xor(partial, 2);
    partial += __shfl_xor(partial, 4);

    if (n < N_NODES && h == 0) {
        float y = partial + lin_b[0];
        int g = batch[n];
        atomicAdd(&gsum[g], y);
        atomicAdd(&gcnt[g], 1.0f);
    }
}

__global__ void k_final(const float* __restrict__ gsum, const float* __restrict__ gcnt,
                        float* __restrict__ out)
{
    int g = threadIdx.x;
    if (g < GRAPHS) out[g] = gsum[g] / fmaxf(gcnt[g], 1.0f);
}

extern "C" void kernel_launch(void* const* d_in, const int* in_sizes, int n_in,
                              void* d_out, int out_size, void* d_ws, size_t ws_size,
                              hipStream_t stream)
{
    const float* pos       = (const float*)d_in[0];
    const int*   z         = (const int*)  d_in[1];
    const int*   edge_index= (const int*)  d_in[2];
    const float* edge_attr = (const float*)d_in[3];
    const int*   batch     = (const int*)  d_in[4];
    const float* emb       = (const float*)d_in[5];
    const float* Wq        = (const float*)d_in[6];
    const float* Wk        = (const float*)d_in[7];
    const float* Wv        = (const float*)d_in[8];
    const float* Wo        = (const float*)d_in[9];
    const float* lin_W     = (const float*)d_in[10];
    const float* lin_b     = (const float*)d_in[11];
    float* out = (float*)d_out;

    char* ws = (char*)d_ws;
    int*   counts  = (int*)ws;                    // 50000
    float* gsum    = (float*)(counts + N_NODES);  // 64
    float* gcnt    = gsum + GRAPHS;               // 64
    int*   offsets = (int*)(gcnt + GRAPHS);       // 50004
    int*   woff    = offsets + 50004;             // 50000
    char*  tail    = (char*)(woff + N_NODES);

    size_t fixed   = (size_t)(tail - ws);
    size_t need2   = fixed + (size_t)N_EDGES * 48 + (size_t)N_NODES * 32 + (size_t)N_NODES * 384;

    hipMemsetAsync(counts, 0, (size_t)(N_NODES + 2 * GRAPHS) * sizeof(int), stream);

    if (ws_size >= need2) {
        float* sein = (float*)tail;                       // E*12 floats (76.8 MB)
        float* x    = sein + (size_t)N_EDGES * 12;        // N*8
        float* qk   = x + N_NODES * 8;                    // N*96

        k_node1      <<<(N_NODES + 31) / 32, 256, 0, stream>>>(pos, z, emb, Wq, Wk, x, qk);
        k_hist       <<<(N_EDGES + 255) / 256, 256, 0, stream>>>(edge_index, counts);
        k_scan       <<<1, SCAN_T, 0, stream>>>(counts, offsets, woff);
        k_scatter_ein<<<(N_EDGES + 255) / 256, 256, 0, stream>>>(edge_index, edge_attr, x, woff, sein);
        k_nodeD2     <<<(N_NODES + 31) / 32, 256, 0, stream>>>(offsets, sein, qk,
                                                               Wv, Wo, lin_W, lin_b, batch, gsum, gcnt);
    } else {
        int2*  sorted = (int2*)tail;                      // E int2 (12.8 MB)
        float* x      = (float*)(sorted + N_EDGES);       // N*8
        float* qk     = x + N_NODES * 8;                  // N*96

        k_node1  <<<(N_NODES + 31) / 32, 256, 0, stream>>>(pos, z, emb, Wq, Wk, x, qk);
        k_hist   <<<(N_EDGES + 255) / 256, 256, 0, stream>>>(edge_index, counts);
        k_scan   <<<1, SCAN_T, 0, stream>>>(counts, offsets, woff);
        k_scatter<<<(N_EDGES + 255) / 256, 256, 0, stream>>>(edge_index, woff, sorted);
        k_nodeD  <<<(N_NODES + 31) / 32, 256, 0, stream>>>(offsets, sorted, x, qk, edge_attr,
                                                           Wv, Wo, lin_W, lin_b, batch, gsum, gcnt);
    }
    k_final<<<1, 64, 0, stream>>>(gsum, gcnt, out);
}